// Round 3
// baseline (524.436 us; speedup 1.0000x reference)
//
#include <hip/hip_runtime.h>
#include <stdint.h>

#define TOKENS 16384
#define D_IN   4096
#define D_OUT  4096
#define NKT    32   // K-tiles of 128 i8

typedef int v4i __attribute__((ext_vector_type(4)));

__device__ __forceinline__ void gl_lds16(const void* g, void* l) {
    __builtin_amdgcn_global_load_lds(
        (const __attribute__((address_space(1))) void*)g,
        (__attribute__((address_space(3))) void*)l, 16, 0, 0);
}

#define BARRIER() __builtin_amdgcn_s_barrier()

__device__ __forceinline__ unsigned sgnb(float f) {
    return (unsigned)(unsigned char)(signed char)((f > 0.f) - (f < 0.f));
}

// ---------------------------------------------------------------------------
// Packed tile-image layout (per 128-row x 128-K-byte unit of 16 KB):
//   slot s = ch*128 + r  <->  signs[row_base + r][k_base + ch*16 .. +16]
// This IS the GEMM's LDS image: global_load_lds stays linear on both sides and
// ds_read_b128 per 8-lane group covers all 32 banks (0 conflicts, verified R2).
//
// Pack kernels: coalesced f32 reads -> sign bytes into padded LDS tile
// (row stride 132 B: writes 2-way free, image-order reads <=4-way) ->
// coalesced 1KB/wave image writes.
// ---------------------------------------------------------------------------

__global__ __launch_bounds__(256) void pack_x_abssum(
        const float* __restrict__ x, signed char* __restrict__ xp,
        float* __restrict__ sum_out) {
    __shared__ unsigned char tile[128 * 132];
    const int b  = blockIdx.x;          // 64*32*2 = 4096 blocks
    const int mt = b >> 6;
    const int kt = (b >> 1) & 31;
    const int h  = b & 1;
    const int t  = threadIdx.x;
    const float* src = x + ((size_t)(mt * 256 + h * 128)) * D_IN + kt * 128;
    float accum = 0.f;
#pragma unroll
    for (int p = 0; p < 16; ++p) {
        const int i  = p * 256 + t;     // float4 index: 128 rows x 32 f4
        const int r  = i >> 5;
        const int c4 = i & 31;
        float4 v = *(const float4*)(src + (size_t)r * D_IN + c4 * 4);
        unsigned w = sgnb(v.x) | (sgnb(v.y) << 8) | (sgnb(v.z) << 16) | (sgnb(v.w) << 24);
        *(unsigned*)&tile[r * 132 + c4 * 4] = w;
        accum += fabsf(v.x) + fabsf(v.y) + fabsf(v.z) + fabsf(v.w);
    }
    __syncthreads();
    unsigned* dst = (unsigned*)(xp + (((size_t)mt * 32 + kt) * 2 + h) * 16384);
#pragma unroll
    for (int p = 0; p < 16; ++p) {
        const int i  = p * 256 + t;     // char4 index in image
        const int s  = i >> 2;
        const int j  = i & 3;
        const int r  = s & 127;
        const int ch = s >> 7;
        dst[i] = *(const unsigned*)&tile[r * 132 + ch * 16 + j * 4];
    }
#pragma unroll
    for (int o = 32; o > 0; o >>= 1) accum += __shfl_down(accum, o);
    if ((t & 63) == 0) atomicAdd(sum_out, accum);
}

__global__ __launch_bounds__(256) void pack_w_kernel(
        const float* __restrict__ wsrc, signed char* __restrict__ wp) {
    __shared__ unsigned char tile[128 * 132];
    const int b  = blockIdx.x;          // 16*32*2 = 1024 blocks
    const int nt = b >> 6;
    const int kt = (b >> 1) & 31;
    const int h  = b & 1;
    const int t  = threadIdx.x;
    const float* src = wsrc + ((size_t)(nt * 256 + h * 128)) * D_IN + kt * 128;
#pragma unroll
    for (int p = 0; p < 16; ++p) {
        const int i  = p * 256 + t;
        const int r  = i >> 5;
        const int c4 = i & 31;
        float4 v = *(const float4*)(src + (size_t)r * D_IN + c4 * 4);
        unsigned w = sgnb(v.x) | (sgnb(v.y) << 8) | (sgnb(v.z) << 16) | (sgnb(v.w) << 24);
        *(unsigned*)&tile[r * 132 + c4 * 4] = w;
    }
    __syncthreads();
    unsigned* dst = (unsigned*)(wp + (((size_t)nt * 32 + kt) * 2 + h) * 16384);
#pragma unroll
    for (int p = 0; p < 16; ++p) {
        const int i  = p * 256 + t;
        const int s  = i >> 2;
        const int j  = i & 3;
        const int r  = s & 127;
        const int ch = s >> 7;
        dst[i] = *(const unsigned*)&tile[r * 132 + ch * 16 + j * 4];
    }
}

// ---------------------------------------------------------------------------
// 256x256 tile, BK=128, 8 waves (2M x 4N), mfma_i32_16x16x64_i8.
// ONE barrier per K-tile: all in-tile reads hit buf d, all stages write d^1,
// so quarters free-run and the compiler pipelines ds_read under MFMA via
// counted lgkmcnt. Tile-end: per-wave vmcnt(0) (stages issued a full tile
// earlier -> no stall) + lgkmcnt(0) (WAR safety) + s_barrier.
// LDS: 2 dbuf x {A0,A1,B0,B1} x 16KB = 128 KB, 1 block/CU.
// ---------------------------------------------------------------------------

#define STG_A(d, kt, h, q) gl_lds16(aS + (size_t)(kt) * 32768 + (h) * 16384 + (q) * 8192, \
                                    (signed char*)&lds[d][h][(q) * 512] + t * 16)
#define STG_B(d, kt, h, q) gl_lds16(bS + (size_t)(kt) * 32768 + (h) * 16384 + (q) * 8192, \
                                    (signed char*)&lds[d][2 + (h)][(q) * 512] + t * 16)

__global__ __launch_bounds__(512, 2) void bin_gemm(
    const signed char* __restrict__ Ap, const signed char* __restrict__ Bp,
    const float* __restrict__ bias, const float* __restrict__ sum_ptr,
    float* __restrict__ out) {
    __shared__ v4i lds[2][4][1024];     // 128 KB

    const int t    = threadIdx.x;       // 0..511
    const int lane = t & 63;
    const int wid  = t >> 6;            // 0..7
    const int wm   = wid >> 2;          // M half (0/1)
    const int wn   = wid & 3;           // N quarter (0..3)
    const int lrow = lane & 15;
    const int lch  = lane >> 4;

    // XCD-aware bijective swizzle (nwg=1024, 1024%8==0)
    const int bid = blockIdx.x;
    const int swz = (bid & 7) * 128 + (bid >> 3);
    const int bn  = swz & 15;           // 16 N-blocks of 256
    const int bm  = swz >> 4;           // 64 M-blocks of 256

    const signed char* aS = Ap + (size_t)bm * (32 * 32768) + (size_t)t * 16;
    const signed char* bS = Bp + (size_t)bn * (32 * 32768) + (size_t)t * 16;

    v4i acc[8][4];
#pragma unroll
    for (int i = 0; i < 8; ++i)
#pragma unroll
        for (int j = 0; j < 4; ++j) acc[i][j] = (v4i){0, 0, 0, 0};

    // prologue: stage tile 0 into dbuf 0
    STG_A(0, 0, 0, 0); STG_A(0, 0, 1, 0); STG_B(0, 0, 0, 0); STG_B(0, 0, 1, 0);
    STG_A(0, 0, 0, 1); STG_A(0, 0, 1, 1); STG_B(0, 0, 0, 1); STG_B(0, 0, 1, 1);
    asm volatile("s_waitcnt vmcnt(0)" ::: "memory");
    BARRIER();

    int d = 0;
    const int bcol = (wn & 1) * 64;
    for (int ktile = 0; ktile < NKT; ++ktile) {
        const bool nx = ktile < NKT - 1;
        const v4i* LA = &lds[d][wm][0];
        const v4i* LB = &lds[d][2 + (wn >> 1)][0];
        v4i af[4], bf[4];

        // ---- Q0: rows 0-63, K-chunk lch (q0 half) ----
#pragma unroll
        for (int fn = 0; fn < 4; ++fn) bf[fn] = LB[lch * 128 + bcol + fn * 16 + lrow];
#pragma unroll
        for (int fr = 0; fr < 4; ++fr) af[fr] = LA[lch * 128 + fr * 16 + lrow];
        if (nx) { STG_A(d ^ 1, ktile + 1, 0, 0); STG_A(d ^ 1, ktile + 1, 1, 0); }
        __builtin_amdgcn_s_setprio(1);
#pragma unroll
        for (int fr = 0; fr < 4; ++fr)
#pragma unroll
            for (int fn = 0; fn < 4; ++fn)
                acc[fr][fn] = __builtin_amdgcn_mfma_i32_16x16x64_i8(af[fr], bf[fn], acc[fr][fn], 0, 0, 0);
        __builtin_amdgcn_s_setprio(0);

        // ---- Q1: rows 64-127, same K-chunk (bf reused) ----
#pragma unroll
        for (int fr = 0; fr < 4; ++fr) af[fr] = LA[lch * 128 + 64 + fr * 16 + lrow];
        if (nx) { STG_B(d ^ 1, ktile + 1, 0, 0); STG_B(d ^ 1, ktile + 1, 1, 0); }
        __builtin_amdgcn_s_setprio(1);
#pragma unroll
        for (int fr = 0; fr < 4; ++fr)
#pragma unroll
            for (int fn = 0; fn < 4; ++fn)
                acc[4 + fr][fn] = __builtin_amdgcn_mfma_i32_16x16x64_i8(af[fr], bf[fn], acc[4 + fr][fn], 0, 0, 0);
        __builtin_amdgcn_s_setprio(0);

        // ---- Q2: rows 0-63, K-chunk 4+lch (q1 half) ----
#pragma unroll
        for (int fn = 0; fn < 4; ++fn) bf[fn] = LB[(4 + lch) * 128 + bcol + fn * 16 + lrow];
#pragma unroll
        for (int fr = 0; fr < 4; ++fr) af[fr] = LA[(4 + lch) * 128 + fr * 16 + lrow];
        if (nx) { STG_A(d ^ 1, ktile + 1, 0, 1); STG_A(d ^ 1, ktile + 1, 1, 1); }
        __builtin_amdgcn_s_setprio(1);
#pragma unroll
        for (int fr = 0; fr < 4; ++fr)
#pragma unroll
            for (int fn = 0; fn < 4; ++fn)
                acc[fr][fn] = __builtin_amdgcn_mfma_i32_16x16x64_i8(af[fr], bf[fn], acc[fr][fn], 0, 0, 0);
        __builtin_amdgcn_s_setprio(0);

        // ---- Q3: rows 64-127, K-chunk 4+lch (bf reused) ----
#pragma unroll
        for (int fr = 0; fr < 4; ++fr) af[fr] = LA[(4 + lch) * 128 + 64 + fr * 16 + lrow];
        if (nx) { STG_B(d ^ 1, ktile + 1, 0, 1); STG_B(d ^ 1, ktile + 1, 1, 1); }
        __builtin_amdgcn_s_setprio(1);
#pragma unroll
        for (int fr = 0; fr < 4; ++fr)
#pragma unroll
            for (int fn = 0; fn < 4; ++fn)
                acc[4 + fr][fn] = __builtin_amdgcn_mfma_i32_16x16x64_i8(af[fr], bf[fn], acc[4 + fr][fn], 0, 0, 0);
        __builtin_amdgcn_s_setprio(0);

        // ---- tile boundary: single sync point ----
        asm volatile("s_waitcnt vmcnt(0) lgkmcnt(0)" ::: "memory");
        BARRIER();
        d ^= 1;
    }

    // epilogue: out = (acc + bias) * scale
    const float scale = *sum_ptr * (1.0f / 67108864.0f);
#pragma unroll
    for (int fn = 0; fn < 4; ++fn) {
        const int col = bn * 256 + wn * 64 + fn * 16 + lrow;
        const float bb = bias[col];
#pragma unroll
        for (int fg = 0; fg < 8; ++fg) {
            const int row0 = bm * 256 + wm * 128 + fg * 16 + lch * 4;
#pragma unroll
            for (int ri = 0; ri < 4; ++ri)
                out[(size_t)(row0 + ri) * D_OUT + col] =
                    ((float)acc[fg][fn][ri] + bb) * scale;
        }
    }
}

extern "C" void kernel_launch(void* const* d_in, const int* in_sizes, int n_in,
                              void* d_out, int out_size, void* d_ws, size_t ws_size,
                              hipStream_t stream) {
    const float* x = (const float*)d_in[0];
    const float* W = (const float*)d_in[1];
    const float* b = (const float*)d_in[2];
    float* out = (float*)d_out;

    float* sum_ptr  = (float*)d_ws;
    signed char* xs = (signed char*)d_ws + 256;
    signed char* wp = xs + (size_t)TOKENS * D_IN;   // +64 MB

    hipMemsetAsync(d_ws, 0, 256, stream);
    pack_x_abssum<<<64 * 32 * 2, 256, 0, stream>>>(x, xs, sum_ptr);
    pack_w_kernel<<<16 * 32 * 2, 256, 0, stream>>>(W, wp);
    bin_gemm<<<1024, 512, 0, stream>>>(xs, wp, b, sum_ptr, out);
}

// Round 4
// 425.410 us; speedup vs baseline: 1.2328x; 1.2328x over previous
//
#include <hip/hip_runtime.h>
#include <stdint.h>

#define TOKENS 16384
#define D_IN   4096
#define D_OUT  4096
#define NKT    32   // K-tiles of 128 i8

typedef int v4i __attribute__((ext_vector_type(4)));

__device__ __forceinline__ void gl_lds16(const void* g, void* l) {
    __builtin_amdgcn_global_load_lds(
        (const __attribute__((address_space(1))) void*)g,
        (__attribute__((address_space(3))) void*)l, 16, 0, 0);
}

#define BARRIER() __builtin_amdgcn_s_barrier()

__device__ __forceinline__ unsigned sgnb(float f) {
    return (unsigned)(unsigned char)(signed char)((f > 0.f) - (f < 0.f));
}

// ---------------------------------------------------------------------------
// Packed tile-image layout per 128-row x 128-K-byte unit (16 KB):
//   slot s = ch*128 + r  <->  signs[row_base + r][k_base + ch*16 .. +16]
// Identical to the GEMM's LDS image: linear global_load_lds on both sides,
// ds_read_b128 bank-conflict-free (verified: SQ_LDS_BANK_CONFLICT = 0).
// ---------------------------------------------------------------------------

__global__ __launch_bounds__(256) void pack_x_abssum(
        const float* __restrict__ x, signed char* __restrict__ xp,
        float* __restrict__ partials) {
    __shared__ unsigned char tile[128 * 132];
    __shared__ float wsum[4];
    const int b  = blockIdx.x;          // 4096 blocks
    const int mt = b >> 6;
    const int kt = (b >> 1) & 31;
    const int h  = b & 1;
    const int t  = threadIdx.x;
    const float* src = x + ((size_t)(mt * 256 + h * 128)) * D_IN + kt * 128;
    float accum = 0.f;
#pragma unroll
    for (int p = 0; p < 16; ++p) {
        const int i  = p * 256 + t;     // float4 index: 128 rows x 32 f4
        const int r  = i >> 5;
        const int c4 = i & 31;
        float4 v = *(const float4*)(src + (size_t)r * D_IN + c4 * 4);
        unsigned w = sgnb(v.x) | (sgnb(v.y) << 8) | (sgnb(v.z) << 16) | (sgnb(v.w) << 24);
        *(unsigned*)&tile[r * 132 + c4 * 4] = w;
        accum += fabsf(v.x) + fabsf(v.y) + fabsf(v.z) + fabsf(v.w);
    }
    __syncthreads();
    unsigned* dst = (unsigned*)(xp + (((size_t)mt * 32 + kt) * 2 + h) * 16384);
#pragma unroll
    for (int p = 0; p < 16; ++p) {
        const int i  = p * 256 + t;
        const int s  = i >> 2;
        const int j  = i & 3;
        const int r  = s & 127;
        const int ch = s >> 7;
        dst[i] = *(const unsigned*)&tile[r * 132 + ch * 16 + j * 4];
    }
    // block-level reduction, ONE write per block (no atomics)
#pragma unroll
    for (int o = 32; o > 0; o >>= 1) accum += __shfl_down(accum, o);
    if ((t & 63) == 0) wsum[t >> 6] = accum;
    __syncthreads();
    if (t == 0) partials[b] = wsum[0] + wsum[1] + wsum[2] + wsum[3];
}

__global__ void reduce_partials(const float* __restrict__ p, float* __restrict__ s) {
    __shared__ float ws[4];
    float a = 0.f;
    for (int i = threadIdx.x; i < 4096; i += 256) a += p[i];
#pragma unroll
    for (int o = 32; o > 0; o >>= 1) a += __shfl_down(a, o);
    if ((threadIdx.x & 63) == 0) ws[threadIdx.x >> 6] = a;
    __syncthreads();
    if (threadIdx.x == 0) s[0] = ws[0] + ws[1] + ws[2] + ws[3];
}

__global__ __launch_bounds__(256) void pack_w_kernel(
        const float* __restrict__ wsrc, signed char* __restrict__ wp) {
    __shared__ unsigned char tile[128 * 132];
    const int b  = blockIdx.x;          // 1024 blocks
    const int nt = b >> 6;
    const int kt = (b >> 1) & 31;
    const int h  = b & 1;
    const int t  = threadIdx.x;
    const float* src = wsrc + ((size_t)(nt * 256 + h * 128)) * D_IN + kt * 128;
#pragma unroll
    for (int p = 0; p < 16; ++p) {
        const int i  = p * 256 + t;
        const int r  = i >> 5;
        const int c4 = i & 31;
        float4 v = *(const float4*)(src + (size_t)r * D_IN + c4 * 4);
        unsigned w = sgnb(v.x) | (sgnb(v.y) << 8) | (sgnb(v.z) << 16) | (sgnb(v.w) << 24);
        *(unsigned*)&tile[r * 132 + c4 * 4] = w;
    }
    __syncthreads();
    unsigned* dst = (unsigned*)(wp + (((size_t)nt * 32 + kt) * 2 + h) * 16384);
#pragma unroll
    for (int p = 0; p < 16; ++p) {
        const int i  = p * 256 + t;
        const int s  = i >> 2;
        const int j  = i & 3;
        const int r  = s & 127;
        const int ch = s >> 7;
        dst[i] = *(const unsigned*)&tile[r * 132 + ch * 16 + j * 4];
    }
}

// ---------------------------------------------------------------------------
// 256x256 tile, BK=128, 8 waves (2M x 4N), mfma_i32_16x16x64_i8.
// SOFTWARE-ROTATED: each phase's fragments are ds_read one phase EARLY into
// named static arrays, so every MFMA cluster's inputs are >=1 cluster old ->
// the compiler's counted lgkmcnt lets the LDS pipe run under the matrix pipe.
// bf is reloaded per-fn INSIDE the ph1 cluster (consume 4 MFMAs, overwrite)
// to keep peak frag regs at 48 (unified total ~252 <= 256, 2 waves/SIMD).
// One barrier per K-tile; vmcnt(0)+lgkmcnt(0) before it (RAW/WAR safe).
// No setprio (no role-split; avoids scheduler fences).
// ---------------------------------------------------------------------------

#define STG_A(d, kt, h, q) gl_lds16(aS + (size_t)(kt) * 32768 + (h) * 16384 + (q) * 8192, \
                                    (signed char*)&lds[d][h][(q) * 512] + t * 16)
#define STG_B(d, kt, h, q) gl_lds16(bS + (size_t)(kt) * 32768 + (h) * 16384 + (q) * 8192, \
                                    (signed char*)&lds[d][2 + (h)][(q) * 512] + t * 16)

#define MFMA(d, a, b) __builtin_amdgcn_mfma_i32_16x16x64_i8((a), (b), (d), 0, 0, 0)

__global__ __launch_bounds__(512, 2) void bin_gemm(
    const signed char* __restrict__ Ap, const signed char* __restrict__ Bp,
    const float* __restrict__ bias, const float* __restrict__ sum_ptr,
    float* __restrict__ out) {
    __shared__ v4i lds[2][4][1024];     // 128 KB

    const int t    = threadIdx.x;       // 0..511
    const int lane = t & 63;
    const int wid  = t >> 6;            // 0..7
    const int wm   = wid >> 2;          // M half (0/1)
    const int wn   = wid & 3;           // N quarter (0..3)
    const int lrow = lane & 15;
    const int lch  = lane >> 4;

    // XCD-aware bijective swizzle (nwg=1024, 1024%8==0)
    const int bid = blockIdx.x;
    const int swz = (bid & 7) * 128 + (bid >> 3);
    const int bn  = swz & 15;
    const int bm  = swz >> 4;

    const signed char* aS = Ap + (size_t)bm * (32 * 32768) + (size_t)t * 16;
    const signed char* bS = Bp + (size_t)bn * (32 * 32768) + (size_t)t * 16;

    v4i acc[8][4];
#pragma unroll
    for (int i = 0; i < 8; ++i)
#pragma unroll
        for (int j = 0; j < 4; ++j) acc[i][j] = (v4i){0, 0, 0, 0};

    // prologue: stage tile 0 into dbuf 0
    STG_A(0, 0, 0, 0); STG_A(0, 0, 1, 0); STG_B(0, 0, 0, 0); STG_B(0, 0, 1, 0);
    STG_A(0, 0, 0, 1); STG_A(0, 0, 1, 1); STG_B(0, 0, 0, 1); STG_B(0, 0, 1, 1);
    asm volatile("s_waitcnt vmcnt(0)" ::: "memory");
    BARRIER();

    int d = 0;
    const int bcol = (wn & 1) * 64;
    v4i afA[4], afB[4], bfA[4];

    for (int kt = 0; kt < NKT; ++kt) {
        const bool nx = kt < NKT - 1;
        const v4i* LA = &lds[d][wm][0];
        const v4i* LB = &lds[d][2 + (wn >> 1)][0];

        // tile-top reads (post-barrier): ph0 inputs
#pragma unroll
        for (int fr = 0; fr < 4; ++fr) afA[fr] = LA[lch * 128 + fr * 16 + lrow];
#pragma unroll
        for (int fn = 0; fn < 4; ++fn) bfA[fn] = LB[lch * 128 + bcol + fn * 16 + lrow];

        // ---- ph0: rows 0-63 x kk0 ---- (prefetch ph1's afB)
#pragma unroll
        for (int fr = 0; fr < 4; ++fr) afB[fr] = LA[lch * 128 + 64 + fr * 16 + lrow];
        if (nx) { STG_A(d ^ 1, kt + 1, 0, 0); STG_A(d ^ 1, kt + 1, 1, 0); }
#pragma unroll
        for (int fr = 0; fr < 4; ++fr)
#pragma unroll
            for (int fn = 0; fn < 4; ++fn)
                acc[fr][fn] = MFMA(acc[fr][fn], afA[fr], bfA[fn]);

        // ---- ph1: rows 64-127 x kk0 ---- (prefetch ph2's afA; reload bf->kk1 per-fn)
#pragma unroll
        for (int fr = 0; fr < 4; ++fr) afA[fr] = LA[(4 + lch) * 128 + fr * 16 + lrow];
        if (nx) { STG_B(d ^ 1, kt + 1, 0, 0); STG_B(d ^ 1, kt + 1, 1, 0); }
#pragma unroll
        for (int fn = 0; fn < 4; ++fn) {
#pragma unroll
            for (int fr = 0; fr < 4; ++fr)
                acc[4 + fr][fn] = MFMA(acc[4 + fr][fn], afB[fr], bfA[fn]);
            bfA[fn] = LB[(4 + lch) * 128 + bcol + fn * 16 + lrow];   // kk1
        }

        // ---- ph2: rows 0-63 x kk1 ---- (prefetch ph3's afB)
#pragma unroll
        for (int fr = 0; fr < 4; ++fr) afB[fr] = LA[(4 + lch) * 128 + 64 + fr * 16 + lrow];
        if (nx) { STG_A(d ^ 1, kt + 1, 0, 1); STG_A(d ^ 1, kt + 1, 1, 1); }
#pragma unroll
        for (int fr = 0; fr < 4; ++fr)
#pragma unroll
            for (int fn = 0; fn < 4; ++fn)
                acc[fr][fn] = MFMA(acc[fr][fn], afA[fr], bfA[fn]);

        // ---- ph3: rows 64-127 x kk1 ----
        if (nx) { STG_B(d ^ 1, kt + 1, 0, 1); STG_B(d ^ 1, kt + 1, 1, 1); }
#pragma unroll
        for (int fr = 0; fr < 4; ++fr)
#pragma unroll
            for (int fn = 0; fn < 4; ++fn)
                acc[4 + fr][fn] = MFMA(acc[4 + fr][fn], afB[fr], bfA[fn]);

        // ---- tile boundary ----
        asm volatile("s_waitcnt vmcnt(0) lgkmcnt(0)" ::: "memory");
        BARRIER();
        d ^= 1;
    }

    // epilogue: out = (acc + bias) * scale
    const float scale = *sum_ptr * (1.0f / 67108864.0f);
#pragma unroll
    for (int fn = 0; fn < 4; ++fn) {
        const int col = bn * 256 + wn * 64 + fn * 16 + lrow;
        const float bb = bias[col];
#pragma unroll
        for (int fg = 0; fg < 8; ++fg) {
            const int row0 = bm * 256 + wm * 128 + fg * 16 + lch * 4;
#pragma unroll
            for (int ri = 0; ri < 4; ++ri)
                out[(size_t)(row0 + ri) * D_OUT + col] =
                    ((float)acc[fg][fn][ri] + bb) * scale;
        }
    }
}

extern "C" void kernel_launch(void* const* d_in, const int* in_sizes, int n_in,
                              void* d_out, int out_size, void* d_ws, size_t ws_size,
                              hipStream_t stream) {
    const float* x = (const float*)d_in[0];
    const float* W = (const float*)d_in[1];
    const float* b = (const float*)d_in[2];
    float* out = (float*)d_out;

    float* sum_ptr   = (float*)d_ws;                 // [0] result
    float* partials  = (float*)d_ws + 64;            // 4096 floats
    signed char* xs  = (signed char*)d_ws + 65536;
    signed char* wp  = xs + (size_t)TOKENS * D_IN;   // +64 MB

    pack_x_abssum<<<64 * 32 * 2, 256, 0, stream>>>(x, xs, partials);
    reduce_partials<<<1, 256, 0, stream>>>(partials, sum_ptr);
    pack_w_kernel<<<16 * 32 * 2, 256, 0, stream>>>(W, wp);
    bin_gemm<<<1024, 512, 0, stream>>>(xs, wp, b, sum_ptr, out);
}

// Round 5
// 356.077 us; speedup vs baseline: 1.4728x; 1.1947x over previous
//
#include <hip/hip_runtime.h>
#include <stdint.h>

#define TOKENS 16384
#define D_IN   4096
#define D_OUT  4096
#define NKT    32   // K-tiles of 128 i8

typedef int v4i __attribute__((ext_vector_type(4)));

__device__ __forceinline__ void gl_lds16(const void* g, void* l) {
    __builtin_amdgcn_global_load_lds(
        (const __attribute__((address_space(1))) void*)g,
        (__attribute__((address_space(3))) void*)l, 16, 0, 0);
}

#define BARRIER() __builtin_amdgcn_s_barrier()
#define LGKM0()  do { asm volatile("s_waitcnt lgkmcnt(0)" ::: "memory"); \
                      __builtin_amdgcn_sched_barrier(0); } while (0)
#define WAIT_VM4() asm volatile("s_waitcnt vmcnt(4)" ::: "memory")
#define WAIT_VM0() asm volatile("s_waitcnt vmcnt(0)" ::: "memory")

__device__ __forceinline__ unsigned sgnb(float f) {
    return (unsigned)(unsigned char)(signed char)((f > 0.f) - (f < 0.f));
}

// ---------------------------------------------------------------------------
// Packed tile-image layout per 128-row x 128-K-byte unit (16 KB):
//   slot s = ch*128 + r  <->  signs[row_base + r][k_base + ch*16 .. +16]
// Identical to the GEMM's LDS image: linear global_load_lds on both sides,
// ds_read_b128 bank-conflict-free (verified: SQ_LDS_BANK_CONFLICT = 0).
// ---------------------------------------------------------------------------

__global__ __launch_bounds__(256) void pack_x_abssum(
        const float* __restrict__ x, signed char* __restrict__ xp,
        float* __restrict__ partials) {
    __shared__ unsigned char tile[128 * 132];
    __shared__ float wsum[4];
    const int b  = blockIdx.x;          // 4096 blocks
    const int mt = b >> 6;
    const int kt = (b >> 1) & 31;
    const int h  = b & 1;
    const int t  = threadIdx.x;
    const float* src = x + ((size_t)(mt * 256 + h * 128)) * D_IN + kt * 128;
    float accum = 0.f;
#pragma unroll
    for (int p = 0; p < 16; ++p) {
        const int i  = p * 256 + t;     // float4 index: 128 rows x 32 f4
        const int r  = i >> 5;
        const int c4 = i & 31;
        float4 v = *(const float4*)(src + (size_t)r * D_IN + c4 * 4);
        unsigned w = sgnb(v.x) | (sgnb(v.y) << 8) | (sgnb(v.z) << 16) | (sgnb(v.w) << 24);
        *(unsigned*)&tile[r * 132 + c4 * 4] = w;
        accum += fabsf(v.x) + fabsf(v.y) + fabsf(v.z) + fabsf(v.w);
    }
    __syncthreads();
    unsigned* dst = (unsigned*)(xp + (((size_t)mt * 32 + kt) * 2 + h) * 16384);
#pragma unroll
    for (int p = 0; p < 16; ++p) {
        const int i  = p * 256 + t;
        const int s  = i >> 2;
        const int j  = i & 3;
        const int r  = s & 127;
        const int ch = s >> 7;
        dst[i] = *(const unsigned*)&tile[r * 132 + ch * 16 + j * 4];
    }
    // deterministic block partial (no atomics -> bit-stable scale)
#pragma unroll
    for (int o = 32; o > 0; o >>= 1) accum += __shfl_down(accum, o);
    if ((t & 63) == 0) wsum[t >> 6] = accum;
    __syncthreads();
    if (t == 0) partials[b] = wsum[0] + wsum[1] + wsum[2] + wsum[3];
}

__global__ void reduce_partials(const float* __restrict__ p, float* __restrict__ s) {
    __shared__ float ws[4];
    float a = 0.f;
    for (int i = threadIdx.x; i < 4096; i += 256) a += p[i];
#pragma unroll
    for (int o = 32; o > 0; o >>= 1) a += __shfl_down(a, o);
    if ((threadIdx.x & 63) == 0) ws[threadIdx.x >> 6] = a;
    __syncthreads();
    if (threadIdx.x == 0) s[0] = ws[0] + ws[1] + ws[2] + ws[3];
}

__global__ __launch_bounds__(256) void pack_w_kernel(
        const float* __restrict__ wsrc, signed char* __restrict__ wp) {
    __shared__ unsigned char tile[128 * 132];
    const int b  = blockIdx.x;          // 1024 blocks
    const int nt = b >> 6;
    const int kt = (b >> 1) & 31;
    const int h  = b & 1;
    const int t  = threadIdx.x;
    const float* src = wsrc + ((size_t)(nt * 256 + h * 128)) * D_IN + kt * 128;
#pragma unroll
    for (int p = 0; p < 16; ++p) {
        const int i  = p * 256 + t;
        const int r  = i >> 5;
        const int c4 = i & 31;
        float4 v = *(const float4*)(src + (size_t)r * D_IN + c4 * 4);
        unsigned w = sgnb(v.x) | (sgnb(v.y) << 8) | (sgnb(v.z) << 16) | (sgnb(v.w) << 24);
        *(unsigned*)&tile[r * 132 + c4 * 4] = w;
    }
    __syncthreads();
    unsigned* dst = (unsigned*)(wp + (((size_t)nt * 32 + kt) * 2 + h) * 16384);
#pragma unroll
    for (int p = 0; p < 16; ++p) {
        const int i  = p * 256 + t;
        const int s  = i >> 2;
        const int j  = i & 3;
        const int r  = s & 127;
        const int ch = s >> 7;
        dst[i] = *(const unsigned*)&tile[r * 132 + ch * 16 + j * 4];
    }
}

// ---------------------------------------------------------------------------
// 256x256 tile, BK=128, 8 waves (2M x 4N), 4 phases/K-tile, counted vmcnt(4).
// R2-proven schedule. NEW: L2-residency swizzle — XCD x (= bid&7, HW
// round-robin) owns bn in {2x, 2x+1}: its 2 MB B-slice stays L2-resident for
// the whole kernel, and the two concurrent same-bm blocks share each A-panel
// fetch. Supply per K-tile: B 32KB from L2 (~585cy) + A ~16KB eff from
// L3/HBM (~820cy) < MFMA 2612cy -> MFMA-bound.
// LDS: 2 dbuf x {A0,A1,B0,B1} x 16KB = 128 KB. 1 block/CU.
// ---------------------------------------------------------------------------

#define STG_A(d, kt, h, q) gl_lds16(aS + (size_t)(kt) * 32768 + (h) * 16384 + (q) * 8192, \
                                    (signed char*)&lds[d][h][(q) * 512] + t * 16)
#define STG_B(d, kt, h, q) gl_lds16(bS + (size_t)(kt) * 32768 + (h) * 16384 + (q) * 8192, \
                                    (signed char*)&lds[d][2 + (h)][(q) * 512] + t * 16)

__global__ __launch_bounds__(512, 2) void bin_gemm(
    const signed char* __restrict__ Ap, const signed char* __restrict__ Bp,
    const float* __restrict__ bias, const float* __restrict__ sum_ptr,
    float* __restrict__ out) {
    __shared__ v4i lds[2][4][1024];     // 128 KB

    const int t    = threadIdx.x;       // 0..511
    const int lane = t & 63;
    const int wid  = t >> 6;            // 0..7
    const int wm   = wid >> 2;          // M half (0/1)
    const int wn   = wid & 3;           // N quarter (0..3)
    const int lrow = lane & 15;
    const int lch  = lane >> 4;

    // B-slice-per-XCD swizzle: XCD = bid&7 owns bn {2x,2x+1}; bm advances
    // slowly so concurrent blocks pair on the same A panel.
    const int bid   = blockIdx.x;
    const int xcd   = bid & 7;
    const int local = bid >> 3;          // 0..127
    const int bn    = xcd * 2 + (local & 1);
    const int bm    = local >> 1;        // 0..63

    const signed char* aS = Ap + (size_t)bm * (32 * 32768) + (size_t)t * 16;
    const signed char* bS = Bp + (size_t)bn * (32 * 32768) + (size_t)t * 16;

    v4i acc[8][4];
#pragma unroll
    for (int i = 0; i < 8; ++i)
#pragma unroll
        for (int j = 0; j < 4; ++j) acc[i][j] = (v4i){0, 0, 0, 0};

    // prologue: stage tile 0 into dbuf 0 in deadline order
    STG_A(0, 0, 0, 0); STG_A(0, 0, 1, 0); STG_B(0, 0, 0, 0); STG_B(0, 0, 1, 0);
    STG_A(0, 0, 0, 1); STG_A(0, 0, 1, 1); STG_B(0, 0, 0, 1); STG_B(0, 0, 1, 1);
    WAIT_VM4();      // q0 halves landed; q1 (4 loads) in flight
    BARRIER();

    int d = 0;
    for (int ktile = 0; ktile < NKT; ++ktile) {
        const bool nx = ktile < NKT - 1;
        const v4i* LA = &lds[d][wm][0];
        const v4i* LB = &lds[d][2 + (wn >> 1)][0];
        const int bcol = (wn & 1) * 64;
        v4i af[4], bf[4];

        // ---- P0: rows 0-63 x kk0 ----
#pragma unroll
        for (int fr = 0; fr < 4; ++fr) af[fr] = LA[lch * 128 + fr * 16 + lrow];
#pragma unroll
        for (int fn = 0; fn < 4; ++fn) bf[fn] = LB[lch * 128 + bcol + fn * 16 + lrow];
        if (nx) { STG_A(d ^ 1, ktile + 1, 0, 0); STG_A(d ^ 1, ktile + 1, 1, 0); }
        BARRIER(); LGKM0();
        __builtin_amdgcn_s_setprio(1);
#pragma unroll
        for (int fr = 0; fr < 4; ++fr)
#pragma unroll
            for (int fn = 0; fn < 4; ++fn)
                acc[fr][fn] = __builtin_amdgcn_mfma_i32_16x16x64_i8(af[fr], bf[fn], acc[fr][fn], 0, 0, 0);
        __builtin_amdgcn_s_setprio(0);
        BARRIER();

        // ---- P1: rows 64-127 x kk0 (bf reused) ----
#pragma unroll
        for (int fr = 0; fr < 4; ++fr) af[fr] = LA[lch * 128 + (4 + fr) * 16 + lrow];
        if (nx) { STG_B(d ^ 1, ktile + 1, 0, 0); STG_B(d ^ 1, ktile + 1, 1, 0); }
        BARRIER(); LGKM0();
        __builtin_amdgcn_s_setprio(1);
#pragma unroll
        for (int fr = 0; fr < 4; ++fr)
#pragma unroll
            for (int fn = 0; fn < 4; ++fn)
                acc[4 + fr][fn] = __builtin_amdgcn_mfma_i32_16x16x64_i8(af[fr], bf[fn], acc[4 + fr][fn], 0, 0, 0);
        __builtin_amdgcn_s_setprio(0);
        if (nx) { WAIT_VM4(); } else { WAIT_VM0(); }   // next phase reads q1
        BARRIER();

        // ---- P2: rows 0-63 x kk1 ----
#pragma unroll
        for (int fr = 0; fr < 4; ++fr) af[fr] = LA[(4 + lch) * 128 + fr * 16 + lrow];
#pragma unroll
        for (int fn = 0; fn < 4; ++fn) bf[fn] = LB[(4 + lch) * 128 + bcol + fn * 16 + lrow];
        if (nx) { STG_A(d ^ 1, ktile + 1, 0, 1); STG_A(d ^ 1, ktile + 1, 1, 1); }
        BARRIER(); LGKM0();
        __builtin_amdgcn_s_setprio(1);
#pragma unroll
        for (int fr = 0; fr < 4; ++fr)
#pragma unroll
            for (int fn = 0; fn < 4; ++fn)
                acc[fr][fn] = __builtin_amdgcn_mfma_i32_16x16x64_i8(af[fr], bf[fn], acc[fr][fn], 0, 0, 0);
        __builtin_amdgcn_s_setprio(0);
        BARRIER();

        // ---- P3: rows 64-127 x kk1 (bf reused) ----
#pragma unroll
        for (int fr = 0; fr < 4; ++fr) af[fr] = LA[(4 + lch) * 128 + (4 + fr) * 16 + lrow];
        if (nx) { STG_B(d ^ 1, ktile + 1, 0, 1); STG_B(d ^ 1, ktile + 1, 1, 1); }
        BARRIER(); LGKM0();
        __builtin_amdgcn_s_setprio(1);
#pragma unroll
        for (int fr = 0; fr < 4; ++fr)
#pragma unroll
            for (int fn = 0; fn < 4; ++fn)
                acc[4 + fr][fn] = __builtin_amdgcn_mfma_i32_16x16x64_i8(af[fr], bf[fn], acc[4 + fr][fn], 0, 0, 0);
        __builtin_amdgcn_s_setprio(0);
        if (nx) { WAIT_VM4(); }        // next tile's P0 reads its q0
        BARRIER();

        d ^= 1;
    }

    // epilogue: out = (acc + bias) * scale
    const float scale = *sum_ptr * (1.0f / 67108864.0f);
#pragma unroll
    for (int fn = 0; fn < 4; ++fn) {
        const int col = bn * 256 + wn * 64 + fn * 16 + lrow;
        const float bb = bias[col];
#pragma unroll
        for (int fg = 0; fg < 8; ++fg) {
            const int row0 = bm * 256 + wm * 128 + fg * 16 + lch * 4;
#pragma unroll
            for (int ri = 0; ri < 4; ++ri)
                out[(size_t)(row0 + ri) * D_OUT + col] =
                    ((float)acc[fg][fn][ri] + bb) * scale;
        }
    }
}

extern "C" void kernel_launch(void* const* d_in, const int* in_sizes, int n_in,
                              void* d_out, int out_size, void* d_ws, size_t ws_size,
                              hipStream_t stream) {
    const float* x = (const float*)d_in[0];
    const float* W = (const float*)d_in[1];
    const float* b = (const float*)d_in[2];
    float* out = (float*)d_out;

    float* sum_ptr   = (float*)d_ws;                 // [0] result
    float* partials  = (float*)d_ws + 64;            // 4096 floats
    signed char* xs  = (signed char*)d_ws + 65536;
    signed char* wp  = xs + (size_t)TOKENS * D_IN;   // +64 MB

    pack_x_abssum<<<64 * 32 * 2, 256, 0, stream>>>(x, xs, partials);
    reduce_partials<<<1, 256, 0, stream>>>(partials, sum_ptr);
    pack_w_kernel<<<16 * 32 * 2, 256, 0, stream>>>(W, wp);
    bin_gemm<<<1024, 512, 0, stream>>>(xs, wp, b, sum_ptr, out);
}

// Round 6
// 349.504 us; speedup vs baseline: 1.5005x; 1.0188x over previous
//
#include <hip/hip_runtime.h>
#include <stdint.h>

#define TOKENS 16384
#define D_IN   4096
#define D_OUT  4096
#define NKT    64   // K-tiles of 64 i8

typedef int v4i  __attribute__((ext_vector_type(4)));
typedef int v16i __attribute__((ext_vector_type(16)));

__device__ __forceinline__ void gl_lds16(const void* g, void* l) {
    __builtin_amdgcn_global_load_lds(
        (const __attribute__((address_space(1))) void*)g,
        (__attribute__((address_space(3))) void*)l, 16, 0, 0);
}

#define BARRIER() __builtin_amdgcn_s_barrier()

__device__ __forceinline__ unsigned sgnb(float f) {
    return (unsigned)(unsigned char)(signed char)((f > 0.f) - (f < 0.f));
}

// ---------------------------------------------------------------------------
// Packed image for 32x32x32 i8 MFMA fragments.
// A: [mb(128)][kt(64)][u(4)][ks(2)][ch(2)][r(32)][16B]   (8 KB per (mb,kt))
//    row = mb*128 + u*32 + r ; k = kt*64 + ks*32 + ch*16 + byte
// B: [nb(16)][kt(64)][u(8)][ks(2)][ch(2)][r(32)][16B]    (16 KB per (nb,kt))
// With this image, the GEMM's gl_lds staging is linear on both sides and each
// fragment ds_read_b128 is lane-linear (addr = base + lane*16): 0 conflicts.
// ---------------------------------------------------------------------------

__global__ __launch_bounds__(256) void pack_x_abssum(
        const float* __restrict__ x, signed char* __restrict__ xp,
        float* __restrict__ partials) {
    __shared__ unsigned char img[16384];   // two 8KB kt-units
    __shared__ float wsum[4];
    const int b   = blockIdx.x;            // 128*32 = 4096 blocks
    const int mb  = b >> 5;
    const int kt2 = b & 31;                // pair of kt units
    const int t   = threadIdx.x;
    const float* src = x + (size_t)mb * 128 * D_IN + kt2 * 128;
    float accum = 0.f;
#pragma unroll
    for (int p = 0; p < 16; ++p) {
        const int idx = p * 256 + t;       // 128 rows x 32 float4
        const int r   = idx >> 5;
        const int c4  = idx & 31;
        float4 v = *(const float4*)(src + (size_t)r * D_IN + c4 * 4);
        unsigned w = sgnb(v.x) | (sgnb(v.y) << 8) | (sgnb(v.z) << 16) | (sgnb(v.w) << 24);
        const int kl = (c4 * 4) & 63;      // k within the 64-k unit
        const int off = ((c4 >= 16) ? 8192 : 0)
                      + (r >> 5) * 2048 + (kl >> 5) * 1024 + ((kl >> 4) & 1) * 512
                      + (r & 31) * 16 + (kl & 15);
        *(unsigned*)&img[off] = w;
        accum += fabsf(v.x) + fabsf(v.y) + fabsf(v.z) + fabsf(v.w);
    }
    __syncthreads();
    unsigned* dst = (unsigned*)(xp + ((size_t)mb * 64 + kt2 * 2) * 8192);
    const unsigned* s32 = (const unsigned*)img;
#pragma unroll
    for (int p = 0; p < 16; ++p) dst[p * 256 + t] = s32[p * 256 + t];
#pragma unroll
    for (int o = 32; o > 0; o >>= 1) accum += __shfl_down(accum, o);
    if ((t & 63) == 0) wsum[t >> 6] = accum;
    __syncthreads();
    if (t == 0) partials[b] = wsum[0] + wsum[1] + wsum[2] + wsum[3];
}

__global__ void reduce_partials(const float* __restrict__ p, float* __restrict__ s) {
    __shared__ float ws[4];
    float a = 0.f;
    for (int i = threadIdx.x; i < 4096; i += 256) a += p[i];
#pragma unroll
    for (int o = 32; o > 0; o >>= 1) a += __shfl_down(a, o);
    if ((threadIdx.x & 63) == 0) ws[threadIdx.x >> 6] = a;
    __syncthreads();
    if (threadIdx.x == 0) s[0] = ws[0] + ws[1] + ws[2] + ws[3];
}

__global__ __launch_bounds__(256) void pack_w_kernel(
        const float* __restrict__ wsrc, signed char* __restrict__ wp) {
    __shared__ unsigned char img[16384];
    const int b  = blockIdx.x;             // 16*64 = 1024 blocks
    const int nb = b >> 6;
    const int kt = b & 63;
    const int t  = threadIdx.x;
    const float* src = wsrc + (size_t)nb * 256 * D_IN + kt * 64;
#pragma unroll
    for (int p = 0; p < 16; ++p) {
        const int idx = p * 256 + t;       // 256 rows x 16 float4
        const int r   = idx >> 4;
        const int c4  = idx & 15;
        float4 v = *(const float4*)(src + (size_t)r * D_IN + c4 * 4);
        unsigned w = sgnb(v.x) | (sgnb(v.y) << 8) | (sgnb(v.z) << 16) | (sgnb(v.w) << 24);
        const int kl = c4 * 4;
        const int off = (r >> 5) * 2048 + (kl >> 5) * 1024 + ((kl >> 4) & 1) * 512
                      + (r & 31) * 16 + (kl & 15);
        *(unsigned*)&img[off] = w;
    }
    __syncthreads();
    unsigned* dst = (unsigned*)(wp + ((size_t)nb * 64 + kt) * 16384);
    const unsigned* s32 = (const unsigned*)img;
#pragma unroll
    for (int p = 0; p < 16; ++p) dst[p * 256 + t] = s32[p * 256 + t];
}

// ---------------------------------------------------------------------------
// 128x256 tile, BK=64, 4 waves (2M x 2N), wave-tile 64x128, mfma_i32_32x32x32.
// TWO blocks/CU (LDS 72KB, 8 waves/CU): cross-block HW overlap of one block's
// MFMA window with the other's LDS/stage window — no lockstep needed.
// Triple-buffered LDS (stage kt+2 while consuming kt) -> per-tile sync is
// exactly {lgkmcnt(0); vmcnt(6); s_barrier}: counted vmcnt waits only for
// loads issued a FULL tile ago (never stalls); one barrier per K-tile.
// Drift-safety: barrier at end of t ensures all reads of buf t%3 are done
// before tile t+1 stages into buf (t+3)%3 == t%3.
// ---------------------------------------------------------------------------

#define STAGE(dstl, kt) do {                                            \
    signed char* L_ = (signed char*)(dstl);                             \
    const signed char* ga_ = aG + (size_t)(kt) * 8192;                  \
    const signed char* gb_ = bG + (size_t)(kt) * 16384;                 \
    gl_lds16(ga_ + t16,         L_ + t16);                              \
    gl_lds16(ga_ + 4096 + t16,  L_ + 4096 + t16);                       \
    gl_lds16(gb_ + t16,         L_ + 8192 + t16);                       \
    gl_lds16(gb_ + 4096 + t16,  L_ + 12288 + t16);                      \
    gl_lds16(gb_ + 8192 + t16,  L_ + 16384 + t16);                      \
    gl_lds16(gb_ + 12288 + t16, L_ + 20480 + t16);                      \
} while (0)

#define MFMA32(d, a, b) __builtin_amdgcn_mfma_i32_32x32x32_i8((a), (b), (d), 0, 0, 0)

__global__ __launch_bounds__(256, 2) void bin_gemm(
    const signed char* __restrict__ Ap, const signed char* __restrict__ Bp,
    const float* __restrict__ bias, const float* __restrict__ sum_ptr,
    float* __restrict__ out) {
    __shared__ v4i lds[3][1536];           // 3 x 24KB = 72KB

    const int t    = threadIdx.x;          // 0..255
    const int t16  = t * 16;
    const int lane = t & 63;
    const int wid  = t >> 6;               // 0..3
    const int wm   = wid >> 1;             // M half (0/1): rows wm*64
    const int wn   = wid & 1;              // N half (0/1): cols wn*128

    // XCD slice: xcd owns nb {2x,2x+1} (1MB packed B per nb -> 2MB L2-resident)
    const int bid   = blockIdx.x;          // 2048 blocks
    const int xcd   = bid & 7;
    const int local = bid >> 3;            // 0..255
    const int nb    = xcd * 2 + (local & 1);   // 0..15
    const int mb    = local >> 1;              // 0..127

    const signed char* aG = Ap + (size_t)mb * 64 * 8192;
    const signed char* bG = Bp + (size_t)nb * 64 * 16384;

    v16i acc[2][4];
#pragma unroll
    for (int i = 0; i < 2; ++i)
#pragma unroll
        for (int j = 0; j < 4; ++j) acc[i][j] = (v16i)(0);

    // prologue: stage kt 0,1 into bufs 0,1
    STAGE(lds[0], 0);
    STAGE(lds[1], 1);
    asm volatile("s_waitcnt vmcnt(6)" ::: "memory");  // kt0 landed
    BARRIER();

    int c = 0, s = 2;                      // consume buf, stage buf
    const int au = wm * 2;                 // A unit base for this wave
    const int bu = wn * 4;                 // B unit base

    for (int kt = 0; kt < NKT; ++kt) {
        const v4i* Lc = &lds[c][0];
        v4i af[2], bf[4];

        // ks = 0 fragments (lane-linear 1KB reads)
#pragma unroll
        for (int am = 0; am < 2; ++am) af[am] = Lc[(au + am) * 128 + lane];
#pragma unroll
        for (int an = 0; an < 4; ++an) bf[an] = Lc[512 + (bu + an) * 128 + lane];
        if (kt < NKT - 2) STAGE(lds[s], kt + 2);
#pragma unroll
        for (int am = 0; am < 2; ++am)
#pragma unroll
            for (int an = 0; an < 4; ++an)
                acc[am][an] = MFMA32(acc[am][an], af[am], bf[an]);

        // ks = 1 fragments
#pragma unroll
        for (int am = 0; am < 2; ++am) af[am] = Lc[(au + am) * 128 + 64 + lane];
#pragma unroll
        for (int an = 0; an < 4; ++an) bf[an] = Lc[512 + (bu + an) * 128 + 64 + lane];
#pragma unroll
        for (int am = 0; am < 2; ++am)
#pragma unroll
            for (int an = 0; an < 4; ++an)
                acc[am][an] = MFMA32(acc[am][an], af[am], bf[an]);

        // tile boundary: drain my ds_reads (WAR), counted vmcnt, one barrier
        if (kt < NKT - 1) {
            asm volatile("s_waitcnt lgkmcnt(0)" ::: "memory");
            if (kt < NKT - 2) { asm volatile("s_waitcnt vmcnt(6)" ::: "memory"); }
            else              { asm volatile("s_waitcnt vmcnt(0)" ::: "memory"); }
            BARRIER();
        }
        c = (c == 2) ? 0 : c + 1;
        s = (s == 2) ? 0 : s + 1;
    }

    // epilogue: out = (acc + bias) * scale
    // 32x32 C/D: col = lane&31, row = (g&3) + 8*(g>>2) + 4*(lane>>5)
    const float scale = *sum_ptr * (1.0f / 67108864.0f);
    const int rbase = mb * 128 + wm * 64 + 4 * (lane >> 5);
    const int cbase = nb * 256 + wn * 128 + (lane & 31);
#pragma unroll
    for (int an = 0; an < 4; ++an) {
        const int col = cbase + an * 32;
        const float bb = bias[col];
#pragma unroll
        for (int am = 0; am < 2; ++am) {
            const int r0 = rbase + am * 32;
#pragma unroll
            for (int g = 0; g < 16; ++g) {
                const int row = r0 + (g & 3) + 8 * (g >> 2);
                out[(size_t)row * D_OUT + col] =
                    ((float)acc[am][an][g] + bb) * scale;
            }
        }
    }
}

extern "C" void kernel_launch(void* const* d_in, const int* in_sizes, int n_in,
                              void* d_out, int out_size, void* d_ws, size_t ws_size,
                              hipStream_t stream) {
    const float* x = (const float*)d_in[0];
    const float* W = (const float*)d_in[1];
    const float* b = (const float*)d_in[2];
    float* out = (float*)d_out;

    float* sum_ptr   = (float*)d_ws;                 // [0] result
    float* partials  = (float*)d_ws + 64;            // 4096 floats
    signed char* xs  = (signed char*)d_ws + 65536;
    signed char* wp  = xs + (size_t)TOKENS * D_IN;   // +64 MB

    pack_x_abssum<<<128 * 32, 256, 0, stream>>>(x, xs, partials);
    reduce_partials<<<1, 256, 0, stream>>>(partials, sum_ptr);
    pack_w_kernel<<<16 * 64, 256, 0, stream>>>(W, wp);
    bin_gemm<<<2048, 256, 0, stream>>>(xs, wp, b, sum_ptr, out);
}